// Round 9
// baseline (179.794 us; speedup 1.0000x reference)
//
#include <hip/hip_runtime.h>

// CostConcatenation: out[b, dd, h, w, :] = valid ? concat(left[b,h,w,:], right[b,h,w-d,:]) : 0
//   d = dd - 48, valid iff 0 <= w-d < 256 (both halves zeroed when invalid).
// left/right [2,64,256,32] f32; out [2,96,64,256,64] f32 (805 MB written once).
//
// R9 theory: all dense-store variants sit at 5.4 TB/s vs 6.8 for the linear-sweep
// fill; NT/occupancy/staging theories falsified. Remaining difference: WRITE
// ADDRESS DISTRIBUTION. Scattered per-block regions -> DRAM row-buffer thrash.
// Fix: block i writes chunk c = s*1024 + i (16 KB) at step s -> the whole chip
// writes ONE contiguous 16 MB window per step, sweeping the output linearly
// (fill-like), while each block's (h, w-window, dd-sequence) stays fixed:
//   c decomposition: wc = i&3 (w0 = wc*64), h = (i>>2)&63, r0 = i>>8,
//   dd = 4s + r0 (mod 96), b = s/24. Store ptr advances 16 MB/step - no decomp.
// LDS per block: 64-px left window + 156-px zero-padded right window + zero slot
// = 28 KB -> 4 blocks/CU, all 1024 resident, 32 waves/CU. Restage at b=0->1.
// Hot loop identical class to R8: cmp + addr-cndmask + ds_read_b128 + dense 8 KB store.

typedef float f4 __attribute__((ext_vector_type(4)));

__global__ __launch_bounds__(512) void cost_concat_kernel(
    const f4* __restrict__ left4,
    const f4* __restrict__ right4,
    f4* __restrict__ out4)
{
    __shared__ f4 lds[1768];  // [0,512) left win | [512,1760) right win (zero-padded) | [1760,1768) zeros

    const int t  = threadIdx.x;        // 0..511
    const int i  = blockIdx.x;         // 0..1023
    const int wc = i & 3;
    const int h  = (i >> 2) & 63;
    const int r0 = i >> 8;             // 0..3  (dd = 4s + r0)
    const int w0 = wc << 6;
    const int idx_lo = w0 - r0 - 44;   // lowest right-image column ever needed

    const int c4 = t & 15;             // f4 within the 64-channel pixel
    const int tb = t >> 4;             // pixel within 32-px half-chunk
    const int cc = c4 & 7;
    const bool isLeft = c4 < 8;
    const int Z = 28160;               // byte addr of zero slot (1760*16)

    const char* lb = (const char*)lds;
    f4* op = out4 + (size_t)i * 1024 + t;   // chunk c=i at s=0; advances 1M f4 (16 MB) per step

    for (int b = 0; b < 2; ++b) {
        const int rowBase = (b * 64 + h) * 2048;   // f4 base of input row (b,h)
        if (b) __syncthreads();                    // drain reads of previous LDS contents

        // stage left window [w0, w0+64): 512 f4, one coalesced load per thread
        lds[t] = left4[rowBase + w0 * 8 + t];
        // stage right window [idx_lo, idx_lo+156), zeros outside [0,256): 1248 f4
        #pragma unroll
        for (int u = 0; u < 3; ++u) {
            const int q = u * 512 + t;
            if (q < 1248) {
                const int col = idx_lo + (q >> 3);
                f4 v = (f4){0.f, 0.f, 0.f, 0.f};
                if ((unsigned)col < 256u) v = right4[rowBase + col * 8 + (q & 7)];
                lds[512 + q] = v;
            }
        }
        if (t < 8) lds[1760 + t] = (f4){0.f, 0.f, 0.f, 0.f};
        __syncthreads();

        // hot-loop registers (reset per b; dd sequence is identical for both b)
        // left  lane j: byte addr ((j*32+tb)*8 + cc)*16, step-invariant
        // right lane j: byte addr (512 + (j*32+tb + 92 - 4*s2)*8 + cc)*16
        int addr0 = isLeft ? ((tb * 8 + cc) * 16)
                           : ((512 + (tb + 92) * 8 + cc) * 16);
        int addr1 = isLeft ? (((32 + tb) * 8 + cc) * 16)
                           : ((512 + (32 + tb + 92) * 8 + cc) * 16);
        int iv0 = w0 + tb + 48 - r0;         // right column for j=0; valid iff in [0,256)
        int iv1 = iv0 + 32;
        const int dec = isLeft ? 0 : 512;

        for (int s2 = 0; s2 < 24; ++s2) {
            const int sel0 = ((unsigned)iv0 < 256u) ? addr0 : Z;
            const int sel1 = ((unsigned)iv1 < 256u) ? addr1 : Z;
            f4 v0 = *(const f4*)(lb + sel0);
            f4 v1 = *(const f4*)(lb + sel1);
            op[0]   = v0;                    // chunk half j=0: 8 KB dense across block
            op[512] = v1;                    // chunk half j=1
            iv0 -= 4; iv1 -= 4;
            addr0 -= dec; addr1 -= dec;
            op += 1048576;                   // next 16 MB window
        }
    }
}

extern "C" void kernel_launch(void* const* d_in, const int* in_sizes, int n_in,
                              void* d_out, int out_size, void* d_ws, size_t ws_size,
                              hipStream_t stream) {
    const f4* left4  = (const f4*)d_in[0];
    const f4* right4 = (const f4*)d_in[1];
    f4* out4 = (f4*)d_out;

    // 1024 blocks x 512 thr, 28 KB LDS -> 4 blocks/CU, all resident, 32 waves/CU.
    cost_concat_kernel<<<1024, 512, 0, stream>>>(left4, right4, out4);
}

// Round 10
// 148.711 us; speedup vs baseline: 1.2090x; 1.2090x over previous
//
#include <hip/hip_runtime.h>

// CostConcatenation: out[b, dd, h, w, :] = valid ? concat(left[b,h,w,:], right[b,h,w-d,:]) : 0
//   d = dd - 48, valid iff 0 <= w-d < 256 (both halves zeroed when invalid).
// Shapes: left/right [2,64,256,32] f32; out [2,96,64,256,64] f32 (805 MB written once).
//
// FINAL (= R4, session best, 149.1 us = ~5.7 TB/s combined HBM traffic, ~90% of
// the 6.29 TB/s copy-ubench ceiling). Structure: stage the (b,h) row of left+right
// into LDS once per block; hot loop = ds_read_b128 (conflict-free) + dense 64 KB
// contiguous stores per k-step. Global reads: one-time 32 MB.
//
// Falsified levers (R5-R9): nontemporal stores, staging-latency hiding via zero
// wedge, register-sourced/segmented wave stores, 4x occupancy (32 waves/CU),
// chip-wide compact write windows. All dense variants land at 149-151 us ->
// memory-side service-rate limit for a 96%-write stream, not a CU-side limit.

typedef float f4 __attribute__((ext_vector_type(4)));

#define DD_STRIDE 262144   // f4 per disparity slice (64*256*16)

__global__ __launch_bounds__(256) void cost_concat_kernel(
    const f4* __restrict__ left4,
    const f4* __restrict__ right4,
    f4* __restrict__ out4)
{
    __shared__ f4 lds[4096];           // [0,2048) = left row, [2048,4096) = right row

    const int t   = threadIdx.x;
    const int blk = blockIdx.x;        // 0..511
    const int g   = blk & 3;           // dd group: dd in [g*24, g*24+24)
    const int hb  = blk >> 2;          // b*64 + h
    const int rowBase = hb * 2048;     // f4 index of input row (256 w * 8 f4)

    // Stage left + right rows (fully coalesced, one-time).
    #pragma unroll
    for (int k = 0; k < 8; ++k)
        lds[k * 256 + t] = left4[rowBase + k * 256 + t];
    #pragma unroll
    for (int k = 0; k < 8; ++k)
        lds[2048 + k * 256 + t] = right4[rowBase + k * 256 + t];
    __syncthreads();

    const int c4  = t & 15;            // float4 within the 64-channel pixel
    const int wb  = t >> 4;            // w low bits (0..15)
    const bool isLeft = c4 < 8;
    const int cc  = c4 & 7;
    const int b   = hb >> 6;
    const int h   = hb & 63;
    const int dd0 = g * 24;

    // out f4 base of (b, dd0, h, 0, 0): row is 4096 f4, written as 24 slices.
    f4* orow = out4 + (size_t)b * 25165824 + (size_t)dd0 * DD_STRIDE + (size_t)h * 4096;

    for (int k = 0; k < 24; ++k) {     // disparity within group
        const int d = dd0 + k - 48;
        f4* op = orow + (size_t)k * DD_STRIDE + t;
        #pragma unroll
        for (int j = 0; j < 16; ++j) { // 16 x 1KB contiguous wave stores cover the slice row
            const int w   = j * 16 + wb;
            const int idx = w - d;                      // right-image column
            const bool valid = (unsigned)idx < 256u;
            const int ci  = valid ? idx : 0;            // masked anyway; keep LDS addr in range
            const int la  = isLeft ? (w * 8 + cc) : (2048 + ci * 8 + cc);
            f4 v = lds[la];
            v = valid ? v : (f4){0.f, 0.f, 0.f, 0.f};
            op[j * 256] = v;
        }
    }
}

extern "C" void kernel_launch(void* const* d_in, const int* in_sizes, int n_in,
                              void* d_out, int out_size, void* d_ws, size_t ws_size,
                              hipStream_t stream) {
    const f4* left4  = (const f4*)d_in[0];
    const f4* right4 = (const f4*)d_in[1];
    f4* out4 = (f4*)d_out;

    // 512 blocks = (hb 128) x (dd-group 4); 64 KB LDS -> 2 blocks/CU, all CUs busy.
    cost_concat_kernel<<<512, 256, 0, stream>>>(left4, right4, out4);
}